// Round 4
// baseline (271.631 us; speedup 1.0000x reference)
//
#include <hip/hip_runtime.h>

#define NRES 256
#define CIN  128
#define NH   4
#define DH   32

typedef __attribute__((ext_vector_type(4))) float f32x4;
typedef __attribute__((ext_vector_type(8))) short bf16x8;
typedef unsigned short u16;

// ---- ws layout (u16 units) ----
#define U_WQG 0                      // [256][128] bf16: rows 0-127 = wq*qsc, 128-255 = wg
#define U_WKV 32768                  // [256][128] bf16: rows 0-127 = wk, 128-255 = wv
#define U_WWO 65536                  // [128][128] bf16: wo[c][e]
#define U_QB  131072                 // [65536][128] bf16 scaled-Q (reused as gated-O)
#define U_KB  (U_QB + 8388608)       // [65536][128] bf16 K
#define U_VT  (U_KB + 8388608)       // [256 n][128 d][256 k] bf16 V^T
#define U_GB  (U_VT + 8388608)       // [65536][128] bf16 sigmoid gate
#define WS_NEED ((size_t)(U_GB + 8388608) * 2)   // 67,371,008 B

// packed RNE fp32->bf16 pair via v_perm
__device__ __forceinline__ unsigned pkbf(float a, float b) {
    unsigned ua = __builtin_bit_cast(unsigned, a);
    unsigned ub = __builtin_bit_cast(unsigned, b);
    ua += 0x7fffu + ((ua >> 16) & 1u);
    ub += 0x7fffu + ((ub >> 16) & 1u);
    return __builtin_amdgcn_perm(ub, ua, 0x07060302);
}
__device__ __forceinline__ u16 f2bfu(float f) {
    unsigned u = __builtin_bit_cast(unsigned, f);
    return (u16)((u + 0x7fffu + ((u >> 16) & 1u)) >> 16);
}
__device__ __forceinline__ float bf2f(u16 v) {
    unsigned u = ((unsigned)v) << 16;
    return __builtin_bit_cast(float, u);
}
union bfr { unsigned u[4]; bf16x8 v; };
__device__ __forceinline__ bf16x8 ldcvt8(const float* __restrict__ p) {
    f32x4 a = *(const f32x4*)p; f32x4 b = *(const f32x4*)(p + 4);
    bfr r;
    r.u[0] = pkbf(a[0], a[1]); r.u[1] = pkbf(a[2], a[3]);
    r.u[2] = pkbf(b[0], b[1]); r.u[3] = pkbf(b[2], b[3]);
    return r.v;
}
__device__ __forceinline__ bf16x8 ldcvt8s(const float* __restrict__ p, float sc) {
    f32x4 a = *(const f32x4*)p; f32x4 b = *(const f32x4*)(p + 4);
    bfr r;
    r.u[0] = pkbf(a[0] * sc, a[1] * sc); r.u[1] = pkbf(a[2] * sc, a[3] * sc);
    r.u[2] = pkbf(b[0] * sc, b[1] * sc); r.u[3] = pkbf(b[2] * sc, b[3] * sc);
    return r.v;
}
#define MFMA(a, b, c) __builtin_amdgcn_mfma_f32_16x16x32_bf16((a), (b), (c), 0, 0, 0)

// ===========================================================================
// Kernel 1: weight pre-convert fp32 -> bf16 (scale folded into wq).
// ===========================================================================
__global__ void wconv(const float* __restrict__ wq, const float* __restrict__ wk,
                      const float* __restrict__ wv, const float* __restrict__ wg,
                      const float* __restrict__ wo, u16* __restrict__ ws)
{
    const int i0 = (blockIdx.x * 256 + threadIdx.x) * 8;
    const float qsc = 0.17677669529663687f;   // 1/sqrt(32)
    const float* src; u16* dst; float sc = 1.f;
    if (i0 < 32768) {
        const int e = i0 >> 7, c = i0 & 127;
        src = (e < 128 ? wq + e * CIN : wg + (e - 128) * CIN) + c;
        if (e < 128) sc = qsc;
        dst = ws + U_WQG + i0;
    } else if (i0 < 65536) {
        const int j = i0 - 32768, e = j >> 7, c = j & 127;
        src = (e < 128 ? wk + e * CIN : wv + (e - 128) * CIN) + c;
        dst = ws + U_WKV + j;
    } else {
        const int j = i0 - 65536;
        src = wo + j; dst = ws + U_WWO + j;
    }
    *(bf16x8*)dst = ldcvt8s(src, sc);
}

// ===========================================================================
// Kernel 2 (FUSED): one block per n (grid 256 = 1 block/CU, 4 waves).
//   Phase 1: all 4 projections for this n's 256 rows -> ws slabs (L2-hot).
//            32 tiles of (64 rows x 64 outs); wave w takes tid = u*4+w.
//            Verbatim R3-proj tile math (R3 blockIdx.x == n*4+rb).
//   Phase 2: flash attention, 4 heads sequential per wave; wave owns q-rows
//            [w*64, w*64+64). Gated O (bf16) overwrites the Q slab: head h's
//            aq (cols h*32..) is loaded BEFORE its O-store (same cols), and
//            earlier heads' stores touch different cols -> no overlap; FIFO
//            vmcnt ordering makes same-wave load-before-store safe.
//   Phase 3: output GEMM on the wave's own 64 rows (verbatim gout math),
//            reading bf16 gated-O directly (fp32 io round-trip eliminated;
//            rounding identical since gout converted fp32->bf16 anyway).
// Rationale: all 4 kernels showed every pipe <20% with dur 4-10x roofline —
// dispatch serialization + ws/io round-trips dominate, so fuse (G11/G15).
// ===========================================================================
#define PST 40   // Pt row stride (u16): 80 B, 16B-aligned
__global__ __launch_bounds__(256) void fused(
    const float* __restrict__ q_x, const float* __restrict__ kv_x,
    const float* __restrict__ bg, const float* __restrict__ mask_bias,
    const float* __restrict__ tri_bias, const float* __restrict__ bo,
    u16* __restrict__ ws, float* __restrict__ out)
{
    const int n = blockIdx.x;
    const int t = threadIdx.x, lane = t & 63, w = t >> 6;
    const int mrow = lane & 15, grp = lane >> 4;
    const int koff = grp * 8, rbase = grp * 4;

    __shared__ u16 Pt[4 * 64 * PST];   // 20480 B per-wave transpose tile
    __shared__ float msk[NRES];

    if (t < 64) *(float4*)&msk[t * 4] = *(const float4*)(mask_bias + n * NRES + t * 4);

    // ---------------- Phase 1: projections ----------------
    #pragma unroll 1
    for (int u = 0; u < 8; ++u) {
        const int tid  = u * 4 + w;
        const int ysel = tid & 1;
        const int rb   = (tid >> 1) & 3;
        const int e0   = ((tid >> 3) & 3) * 64;
        const int R0   = n * 256 + rb * 64;
        const float* __restrict__ src = ysel ? kv_x : q_x;
        const u16* __restrict__ W = ws + (ysel ? U_WKV : U_WQG);
        const bool vpath = ysel && (e0 >= 128);

        const f32x4 zf = {0.f, 0.f, 0.f, 0.f};
        f32x4 acc[4][4];
        #pragma unroll
        for (int mt = 0; mt < 4; ++mt)
            #pragma unroll
            for (int nt = 0; nt < 4; ++nt) acc[mt][nt] = zf;

        if (!vpath) {
            #pragma unroll 2
            for (int ct = 0; ct < 4; ++ct) {
                const int c0 = ct * 32 + koff;
                const bf16x8 bw0 = *(const bf16x8*)(W + (e0 +  0 + mrow) * CIN + c0);
                const bf16x8 bw1 = *(const bf16x8*)(W + (e0 + 16 + mrow) * CIN + c0);
                const bf16x8 bw2 = *(const bf16x8*)(W + (e0 + 32 + mrow) * CIN + c0);
                const bf16x8 bw3 = *(const bf16x8*)(W + (e0 + 48 + mrow) * CIN + c0);
                #pragma unroll
                for (int mt = 0; mt < 4; ++mt) {
                    const bf16x8 aX = ldcvt8(src + (size_t)(R0 + mt * 16 + mrow) * CIN + c0);
                    acc[mt][0] = MFMA(bw0, aX, acc[mt][0]);   // D[e][row]
                    acc[mt][1] = MFMA(bw1, aX, acc[mt][1]);
                    acc[mt][2] = MFMA(bw2, aX, acc[mt][2]);
                    acc[mt][3] = MFMA(bw3, aX, acc[mt][3]);
                }
            }
        } else {
            #pragma unroll 2
            for (int ct = 0; ct < 4; ++ct) {
                const int c0 = ct * 32 + koff;
                const bf16x8 bw0 = *(const bf16x8*)(W + (e0 +  0 + mrow) * CIN + c0);
                const bf16x8 bw1 = *(const bf16x8*)(W + (e0 + 16 + mrow) * CIN + c0);
                const bf16x8 bw2 = *(const bf16x8*)(W + (e0 + 32 + mrow) * CIN + c0);
                const bf16x8 bw3 = *(const bf16x8*)(W + (e0 + 48 + mrow) * CIN + c0);
                #pragma unroll
                for (int mt = 0; mt < 4; ++mt) {
                    const bf16x8 aX = ldcvt8(src + (size_t)(R0 + mt * 16 + mrow) * CIN + c0);
                    acc[mt][0] = MFMA(aX, bw0, acc[mt][0]);   // D[row][d]
                    acc[mt][1] = MFMA(aX, bw1, acc[mt][1]);
                    acc[mt][2] = MFMA(aX, bw2, acc[mt][2]);
                    acc[mt][3] = MFMA(aX, bw3, acc[mt][3]);
                }
            }
        }

        if (!ysel) {
            if (e0 < 128) {            // Q
                #pragma unroll
                for (int mt = 0; mt < 4; ++mt) {
                    const size_t row = (size_t)(R0 + mt * 16 + mrow);
                    #pragma unroll
                    for (int nt = 0; nt < 4; ++nt) {
                        uint2 v;
                        v.x = pkbf(acc[mt][nt][0], acc[mt][nt][1]);
                        v.y = pkbf(acc[mt][nt][2], acc[mt][nt][3]);
                        *(uint2*)&ws[U_QB + row * CIN + e0 + nt * 16 + rbase] = v;
                    }
                }
            } else {                   // G = sigmoid(logit + bg[e])
                #pragma unroll
                for (int mt = 0; mt < 4; ++mt) {
                    const size_t row = (size_t)(R0 + mt * 16 + mrow);
                    #pragma unroll
                    for (int nt = 0; nt < 4; ++nt) {
                        const int eb = (e0 - 128) + nt * 16 + rbase;
                        const f32x4 bgv = *(const f32x4*)(bg + eb);
                        float g[4];
                        #pragma unroll
                        for (int r = 0; r < 4; ++r)
                            g[r] = 1.f / (1.f + __expf(-(acc[mt][nt][r] + bgv[r])));
                        uint2 v;
                        v.x = pkbf(g[0], g[1]);
                        v.y = pkbf(g[2], g[3]);
                        *(uint2*)&ws[U_GB + row * CIN + eb] = v;
                    }
                }
            }
        } else {
            if (e0 < 128) {            // K
                #pragma unroll
                for (int mt = 0; mt < 4; ++mt) {
                    const size_t row = (size_t)(R0 + mt * 16 + mrow);
                    #pragma unroll
                    for (int nt = 0; nt < 4; ++nt) {
                        uint2 v;
                        v.x = pkbf(acc[mt][nt][0], acc[mt][nt][1]);
                        v.y = pkbf(acc[mt][nt][2], acc[mt][nt][3]);
                        *(uint2*)&ws[U_KB + row * CIN + e0 + nt * 16 + rbase] = v;
                    }
                }
            } else {                   // V^T [n][d][k]
                #pragma unroll
                for (int mt = 0; mt < 4; ++mt) {
                    const int k0 = rb * 64 + mt * 16 + rbase;
                    #pragma unroll
                    for (int nt = 0; nt < 4; ++nt) {
                        const int d = (e0 - 128) + nt * 16 + mrow;
                        uint2 v;
                        v.x = pkbf(acc[mt][nt][0], acc[mt][nt][1]);
                        v.y = pkbf(acc[mt][nt][2], acc[mt][nt][3]);
                        *(uint2*)&ws[U_VT + ((size_t)n * 128 + d) * 256 + k0] = v;
                    }
                }
            }
        }
    }

    __syncthreads();   // all ws slabs for this n + msk visible

    // ---------------- Phase 2: attention, 4 heads ----------------
    u16* __restrict__ QOg = ws + U_QB + (size_t)n * NRES * CIN;  // Q in, gated-O out
    const u16* __restrict__ Kb = ws + U_KB + (size_t)n * NRES * CIN;
    const u16* __restrict__ Vt = ws + U_VT + (size_t)n * 128 * 256;
    const u16* __restrict__ Gb = ws + U_GB + (size_t)n * NRES * CIN;
    const int q0 = w * 64;
    const f32x4 zf = {0.f, 0.f, 0.f, 0.f};
    u16* __restrict__ pw = &Pt[w * 64 * PST];

    #pragma unroll 1
    for (int h = 0; h < 4; ++h) {
        bf16x8 aqh[4];
        #pragma unroll
        for (int qt = 0; qt < 4; ++qt)
            aqh[qt] = *(const bf16x8*)(QOg + (size_t)(q0 + qt * 16 + mrow) * CIN + h * DH + koff);

        f32x4 oa[4][2], ls4[4];
        #pragma unroll
        for (int qt = 0; qt < 4; ++qt) { oa[qt][0] = zf; oa[qt][1] = zf; ls4[qt] = zf; }

        const float* __restrict__ trih = tri_bias + (size_t)h * NRES * NRES;

        for (int kt = 0; kt < 8; ++kt) {
            const int kb = kt * 32;
            bf16x8 bk0 = *(const bf16x8*)(Kb + (size_t)(kb + mrow) * CIN + h * DH + koff);
            bf16x8 bk1 = *(const bf16x8*)(Kb + (size_t)(kb + 16 + mrow) * CIN + h * DH + koff);
            bf16x8 bv0 = *(const bf16x8*)(Vt + (size_t)(h * DH + mrow) * NRES + kb + koff);
            bf16x8 bv1 = *(const bf16x8*)(Vt + (size_t)(h * DH + 16 + mrow) * NRES + kb + koff);
            const float mb0 = msk[kb + mrow] - 8.f;
            const float mb1 = msk[kb + 16 + mrow] - 8.f;

            #pragma unroll
            for (int h2 = 0; h2 < 2; ++h2) {
                float tr0[2][4], tr1[2][4];
                #pragma unroll
                for (int j = 0; j < 2; ++j) {
                    const int qt = h2 * 2 + j;
                    const float* __restrict__ trow =
                        trih + (q0 + qt * 16 + rbase) * NRES + kb + mrow;
                    #pragma unroll
                    for (int r = 0; r < 4; ++r) {
                        tr0[j][r] = trow[r * NRES];
                        tr1[j][r] = trow[r * NRES + 16];
                    }
                }
                #pragma unroll
                for (int j = 0; j < 2; ++j) {
                    const int qt = h2 * 2 + j;
                    f32x4 s0 = MFMA(aqh[qt], bk0, zf);
                    f32x4 s1 = MFMA(aqh[qt], bk1, zf);
                    #pragma unroll
                    for (int r = 0; r < 4; ++r) {
                        s0[r] = __expf(s0[r] + tr0[j][r] + mb0);
                        s1[r] = __expf(s1[r] + tr1[j][r] + mb1);
                    }
                    ls4[qt] += s0 + s1;
                    #pragma unroll
                    for (int r = 0; r < 4; ++r) {
                        pw[(qt * 16 + rbase + r) * PST + mrow]      = f2bfu(s0[r]);
                        pw[(qt * 16 + rbase + r) * PST + 16 + mrow] = f2bfu(s1[r]);
                    }
                }
            }
            asm volatile("s_waitcnt lgkmcnt(0)" ::: "memory");   // one drain per kt
            #pragma unroll
            for (int qt = 0; qt < 4; ++qt) {
                bf16x8 pa = *(const bf16x8*)&pw[(qt * 16 + mrow) * PST + koff];
                oa[qt][0] = MFMA(pa, bv0, oa[qt][0]);
                oa[qt][1] = MFMA(pa, bv1, oa[qt][1]);
            }
        }

        // epilogue: normalize + gate, store gated O (bf16) over the Q slab
        #pragma unroll
        for (int qt = 0; qt < 4; ++qt) {
            f32x4 lv = ls4[qt];
            #pragma unroll
            for (int xm = 1; xm < 16; xm <<= 1) {
                lv[0] += __shfl_xor(lv[0], xm, 64);
                lv[1] += __shfl_xor(lv[1], xm, 64);
                lv[2] += __shfl_xor(lv[2], xm, 64);
                lv[3] += __shfl_xor(lv[3], xm, 64);
            }
            #pragma unroll
            for (int r = 0; r < 4; ++r) {
                const float inv = 1.f / lv[r];
                const int q = q0 + qt * 16 + rbase + r;
                const float g0 = bf2f(Gb[(size_t)q * CIN + h * DH + mrow]);
                const float g1 = bf2f(Gb[(size_t)q * CIN + h * DH + 16 + mrow]);
                QOg[(size_t)q * CIN + h * DH + mrow]      = f2bfu(oa[qt][0][r] * inv * g0);
                QOg[(size_t)q * CIN + h * DH + 16 + mrow] = f2bfu(oa[qt][1][r] * inv * g1);
            }
        }
    }

    // same-wave store->load ordering on the O slab (no cross-wave dependency:
    // each wave reads only its own 64 rows)
    asm volatile("s_waitcnt vmcnt(0)" ::: "memory");

    // ---------------- Phase 3: output GEMM (own 64 rows) ----------------
    const u16* __restrict__ Wo = ws + U_WWO;
    float* __restrict__ outn = out + (size_t)n * NRES * CIN;
    #pragma unroll 1
    for (int sb = 0; sb < 2; ++sb) {
        const int r0s = q0 + sb * 32;
        f32x4 acc2[2][8];
        #pragma unroll
        for (int at = 0; at < 2; ++at)
            #pragma unroll
            for (int nt = 0; nt < 8; ++nt) acc2[at][nt] = zf;

        #pragma unroll
        for (int ks = 0; ks < 4; ++ks) {
            const int e0k = ks * 32 + koff;
            const bf16x8 a0 = *(const bf16x8*)(QOg + (size_t)(r0s + mrow) * CIN + e0k);
            const bf16x8 a1 = *(const bf16x8*)(QOg + (size_t)(r0s + 16 + mrow) * CIN + e0k);
            #pragma unroll
            for (int nt = 0; nt < 8; ++nt) {
                const bf16x8 bw = *(const bf16x8*)(Wo + (nt * 16 + mrow) * CIN + e0k);
                acc2[0][nt] = MFMA(a0, bw, acc2[0][nt]);
                acc2[1][nt] = MFMA(a1, bw, acc2[1][nt]);
            }
        }

        #pragma unroll
        for (int nt = 0; nt < 8; ++nt) {
            const float bc = bo[nt * 16 + mrow];
            #pragma unroll
            for (int at = 0; at < 2; ++at)
                #pragma unroll
                for (int r = 0; r < 4; ++r)
                    outn[(size_t)(r0s + at * 16 + rbase + r) * CIN + nt * 16 + mrow] =
                        acc2[at][nt][r] + bc;
        }
    }
}

// ===========================================================================
// Fallback path (R3 kernels, proven correct) for small ws_size.
// ===========================================================================
#define KST 32
#define VST 264
#define GST 136

__global__ __launch_bounds__(256, 3) void attn_fb(
    const float* __restrict__ q_x, const float* __restrict__ kv_x,
    const float* __restrict__ mask_bias, const float* __restrict__ tri_bias,
    const float* __restrict__ wq, const float* __restrict__ wk,
    const float* __restrict__ wv, float* __restrict__ o_out)
{
    const int h = blockIdx.x, n = blockIdx.y;
    const int t = threadIdx.x;
    const int lane = t & 63, w = t >> 6;
    const int mrow = lane & 15;
    const int grp  = lane >> 4;
    const int koff = grp * 8;
    const int rbase = grp * 4;
    const int q0 = w * 64;

    __shared__ u16 Ks[NRES * KST];
    __shared__ u16 Vt[DH * VST];
    __shared__ u16 Ptb[4 * 32 * PST];
    __shared__ float msk[NRES];

    if (t < 64) *(float4*)&msk[t * 4] = *(const float4*)(mask_bias + n * NRES + t * 4);

    const float* __restrict__ qxn = q_x  + (size_t)n * NRES * CIN;
    const float* __restrict__ kxn = kv_x + (size_t)n * NRES * CIN;
    const float* __restrict__ wqh = wq + h * DH * CIN;
    const float* __restrict__ wkh = wk + h * DH * CIN;
    const float* __restrict__ wvh = wv + h * DH * CIN;

    f32x4 aq_[4][2], ak_[4][2], av_[4][2];
    const f32x4 zf = {0.f, 0.f, 0.f, 0.f};
    #pragma unroll
    for (int qt = 0; qt < 4; ++qt)
        #pragma unroll
        for (int dt = 0; dt < 2; ++dt) { aq_[qt][dt] = zf; ak_[qt][dt] = zf; av_[qt][dt] = zf; }

    const float qsc = 0.17677669529663687f;
    #pragma unroll
    for (int ct = 0; ct < 4; ++ct) {
        const int c0 = ct * 32 + koff;
        bf16x8 bq0 = ldcvt8s(wqh + mrow * CIN + c0, qsc);
        bf16x8 bq1 = ldcvt8s(wqh + (16 + mrow) * CIN + c0, qsc);
        bf16x8 bk0 = ldcvt8(wkh + mrow * CIN + c0);
        bf16x8 bk1 = ldcvt8(wkh + (16 + mrow) * CIN + c0);
        bf16x8 bv0 = ldcvt8(wvh + mrow * CIN + c0);
        bf16x8 bv1 = ldcvt8(wvh + (16 + mrow) * CIN + c0);
        #pragma unroll
        for (int qt = 0; qt < 4; ++qt) {
            bf16x8 aX = ldcvt8(qxn + (q0 + qt * 16 + mrow) * CIN + c0);
            aq_[qt][0] = MFMA(aX, bq0, aq_[qt][0]);
            aq_[qt][1] = MFMA(aX, bq1, aq_[qt][1]);
            bf16x8 aK = ldcvt8(kxn + (q0 + qt * 16 + mrow) * CIN + c0);
            ak_[qt][0] = MFMA(aK, bk0, ak_[qt][0]);
            ak_[qt][1] = MFMA(aK, bk1, ak_[qt][1]);
            av_[qt][0] = MFMA(aK, bv0, av_[qt][0]);
            av_[qt][1] = MFMA(aK, bv1, av_[qt][1]);
        }
    }

    #pragma unroll
    for (int qt = 0; qt < 4; ++qt)
        #pragma unroll
        for (int dt = 0; dt < 2; ++dt)
            #pragma unroll
            for (int r = 0; r < 4; ++r) {
                const int row = q0 + qt * 16 + rbase + r;
                const int d = dt * 16 + mrow;
                Ks[row * KST + d] = f2bfu(ak_[qt][dt][r]);
                Vt[d * VST + row] = f2bfu(av_[qt][dt][r]);
            }

    u16* __restrict__ pw = &Ptb[w * 32 * PST];
    bf16x8 aq[4];
    #pragma unroll
    for (int h2 = 0; h2 < 2; ++h2) {
        #pragma unroll
        for (int j = 0; j < 2; ++j) {
            const int qt = h2 * 2 + j;
            #pragma unroll
            for (int dt = 0; dt < 2; ++dt)
                #pragma unroll
                for (int r = 0; r < 4; ++r)
                    pw[(j * 16 + rbase + r) * PST + dt * 16 + mrow] = f2bfu(aq_[qt][dt][r]);
        }
        asm volatile("s_waitcnt lgkmcnt(0)" ::: "memory");
        #pragma unroll
        for (int j = 0; j < 2; ++j)
            aq[h2 * 2 + j] = *(const bf16x8*)&pw[(j * 16 + mrow) * PST + koff];
        asm volatile("s_waitcnt lgkmcnt(0)" ::: "memory");
    }
    __syncthreads();

    f32x4 oa[4][2], ls4[4];
    #pragma unroll
    for (int qt = 0; qt < 4; ++qt) { oa[qt][0] = zf; oa[qt][1] = zf; ls4[qt] = zf; }

    const float* __restrict__ trih = tri_bias + (size_t)h * NRES * NRES;

    for (int kt = 0; kt < 8; ++kt) {
        const int kb = kt * 32;
        bf16x8 bk0 = *(const bf16x8*)&Ks[(kb + mrow) * KST + koff];
        bf16x8 bk1 = *(const bf16x8*)&Ks[(kb + 16 + mrow) * KST + koff];
        bf16x8 bv0 = *(const bf16x8*)&Vt[mrow * VST + kb + koff];
        bf16x8 bv1 = *(const bf16x8*)&Vt[(16 + mrow) * VST + kb + koff];
        const float mb0 = msk[kb + mrow] - 8.f;
        const float mb1 = msk[kb + 16 + mrow] - 8.f;

        #pragma unroll
        for (int h2 = 0; h2 < 2; ++h2) {
            float tr0[2][4], tr1[2][4];
            #pragma unroll
            for (int j = 0; j < 2; ++j) {
                const int qt = h2 * 2 + j;
                const float* __restrict__ trow =
                    trih + (q0 + qt * 16 + rbase) * NRES + kb + mrow;
                #pragma unroll
                for (int r = 0; r < 4; ++r) {
                    tr0[j][r] = trow[r * NRES];
                    tr1[j][r] = trow[r * NRES + 16];
                }
            }
            #pragma unroll
            for (int j = 0; j < 2; ++j) {
                const int qt = h2 * 2 + j;
                f32x4 s0 = MFMA(aq[qt], bk0, zf);
                f32x4 s1 = MFMA(aq[qt], bk1, zf);
                #pragma unroll
                for (int r = 0; r < 4; ++r) {
                    s0[r] = __expf(s0[r] + tr0[j][r] + mb0);
                    s1[r] = __expf(s1[r] + tr1[j][r] + mb1);
                }
                ls4[qt] += s0 + s1;
                #pragma unroll
                for (int r = 0; r < 4; ++r) {
                    pw[(j * 16 + rbase + r) * PST + mrow]      = f2bfu(s0[r]);
                    pw[(j * 16 + rbase + r) * PST + 16 + mrow] = f2bfu(s1[r]);
                }
            }
            asm volatile("s_waitcnt lgkmcnt(0)" ::: "memory");
            #pragma unroll
            for (int j = 0; j < 2; ++j) {
                const int qt = h2 * 2 + j;
                bf16x8 pa = *(const bf16x8*)&pw[(j * 16 + mrow) * PST + koff];
                oa[qt][0] = MFMA(pa, bv0, oa[qt][0]);
                oa[qt][1] = MFMA(pa, bv1, oa[qt][1]);
            }
        }
    }

    float* __restrict__ orow = o_out + (size_t)n * NRES * CIN + h * DH;
    #pragma unroll
    for (int qt = 0; qt < 4; ++qt) {
        f32x4 lv = ls4[qt];
        #pragma unroll
        for (int xm = 1; xm < 16; xm <<= 1) {
            lv[0] += __shfl_xor(lv[0], xm, 64);
            lv[1] += __shfl_xor(lv[1], xm, 64);
            lv[2] += __shfl_xor(lv[2], xm, 64);
            lv[3] += __shfl_xor(lv[3], xm, 64);
        }
        #pragma unroll
        for (int r = 0; r < 4; ++r) {
            const float inv = 1.f / lv[r];
            const int q = q0 + qt * 16 + rbase + r;
            orow[q * CIN + mrow]      = oa[qt][0][r] * inv;
            orow[q * CIN + 16 + mrow] = oa[qt][1][r] * inv;
        }
    }
}

__global__ __launch_bounds__(256, 4) void gate_fb(
    const float* __restrict__ q_x, const float* __restrict__ wg,
    const float* __restrict__ bg, const float* __restrict__ wo,
    const float* __restrict__ bo, float* io)
{
    const int t = threadIdx.x;
    const int lane = t & 63, w = t >> 6;
    const int mrow = lane & 15, grp = lane >> 4;
    const int koff = grp * 8, rbase = grp * 4;
    const int r0 = blockIdx.x * 128 + w * 32;

    __shared__ u16 Gt[4 * 32 * GST];
    u16* __restrict__ gw = &Gt[w * 32 * GST];

    const f32x4 zf = {0.f, 0.f, 0.f, 0.f};
    f32x4 acc[2][8];
    #pragma unroll
    for (int at = 0; at < 2; ++at)
        #pragma unroll
        for (int nt = 0; nt < 8; ++nt) acc[at][nt] = zf;

    #pragma unroll
    for (int ks = 0; ks < 4; ++ks) {
        const int c0 = ks * 32 + koff;
        bf16x8 ax0 = ldcvt8(q_x + (size_t)(r0 + mrow) * CIN + c0);
        bf16x8 ax1 = ldcvt8(q_x + (size_t)(r0 + 16 + mrow) * CIN + c0);
        #pragma unroll
        for (int nt = 0; nt < 8; ++nt) {
            bf16x8 bw = ldcvt8(wg + (nt * 16 + mrow) * CIN + c0);
            acc[0][nt] = MFMA(ax0, bw, acc[0][nt]);
            acc[1][nt] = MFMA(ax1, bw, acc[1][nt]);
        }
    }

    #pragma unroll
    for (int nt = 0; nt < 8; ++nt) {
        const float bge = bg[nt * 16 + mrow];
        #pragma unroll
        for (int at = 0; at < 2; ++at)
            #pragma unroll
            for (int r = 0; r < 4; ++r) {
                const int qg = r0 + at * 16 + rbase + r;
                const float ov = io[(size_t)qg * CIN + nt * 16 + mrow];
                const float g = 1.f / (1.f + __expf(-(acc[at][nt][r] + bge)));
                gw[(at * 16 + rbase + r) * GST + nt * 16 + mrow] = f2bfu(ov * g);
            }
    }
    asm volatile("s_waitcnt lgkmcnt(0)" ::: "memory");

    f32x4 acc2[2][8];
    #pragma unroll
    for (int at = 0; at < 2; ++at)
        #pragma unroll
        for (int nt = 0; nt < 8; ++nt) acc2[at][nt] = zf;

    #pragma unroll
    for (int ks = 0; ks < 4; ++ks) {
        const int e0 = ks * 32 + koff;
        bf16x8 ag0 = *(const bf16x8*)&gw[mrow * GST + e0];
        bf16x8 ag1 = *(const bf16x8*)&gw[(16 + mrow) * GST + e0];
        #pragma unroll
        for (int nt = 0; nt < 8; ++nt) {
            bf16x8 bw = ldcvt8(wo + (nt * 16 + mrow) * CIN + e0);
            acc2[0][nt] = MFMA(ag0, bw, acc2[0][nt]);
            acc2[1][nt] = MFMA(ag1, bw, acc2[1][nt]);
        }
    }

    #pragma unroll
    for (int nt = 0; nt < 8; ++nt) {
        const float boc = bo[nt * 16 + mrow];
        #pragma unroll
        for (int at = 0; at < 2; ++at)
            #pragma unroll
            for (int r = 0; r < 4; ++r)
                io[(size_t)(r0 + at * 16 + rbase + r) * CIN + nt * 16 + mrow] =
                    acc2[at][nt][r] + boc;
    }
}

extern "C" void kernel_launch(void* const* d_in, const int* in_sizes, int n_in,
                              void* d_out, int out_size, void* d_ws, size_t ws_size,
                              hipStream_t stream) {
    const float* q_x  = (const float*)d_in[0];
    const float* kv_x = (const float*)d_in[1];
    const float* mask = (const float*)d_in[2];
    const float* tri  = (const float*)d_in[3];
    const float* wq   = (const float*)d_in[4];
    const float* wk   = (const float*)d_in[5];
    const float* wv   = (const float*)d_in[6];
    const float* wg   = (const float*)d_in[7];
    const float* bg   = (const float*)d_in[8];
    const float* wo   = (const float*)d_in[9];
    const float* bo   = (const float*)d_in[10];
    float* out = (float*)d_out;

    if (ws_size >= WS_NEED) {
        u16* ws16 = (u16*)d_ws;
        wconv<<<40, 256, 0, stream>>>(wq, wk, wv, wg, wo, ws16);
        fused<<<NRES, 256, 0, stream>>>(q_x, kv_x, bg, mask, tri, bo, ws16, out);
    } else {
        attn_fb<<<dim3(NH, NRES), 256, 0, stream>>>(q_x, kv_x, mask, tri, wq, wk, wv, out);
        gate_fb<<<(NRES * NRES) / 128, 256, 0, stream>>>(q_x, wg, bg, wo, bo, out);
    }
}

// Round 5
// 247.070 us; speedup vs baseline: 1.0994x; 1.0994x over previous
//
#include <hip/hip_runtime.h>

#define NRES 256
#define CIN  128
#define NH   4
#define DH   32

typedef __attribute__((ext_vector_type(4))) float f32x4;
typedef __attribute__((ext_vector_type(8))) short bf16x8;
typedef unsigned short u16;

// ---- ws layout (u16 units) ----
#define U_WQG 0                      // [256][128] bf16: rows 0-127 = wq*qsc, 128-255 = wg
#define U_WKV 32768                  // [256][128] bf16: rows 0-127 = wk, 128-255 = wv
#define U_WWO 65536                  // [128][128] bf16: wo[c][e]
#define U_QB  131072                 // [65536][128] bf16 scaled-Q (reused as gated-O)
#define U_KB  (U_QB + 8388608)       // [65536][128] bf16 K
#define U_VT  (U_KB + 8388608)       // [256 n][128 d][256 k] bf16 V^T
#define U_GB  (U_VT + 8388608)       // [65536][128] bf16 sigmoid gate
#define WS_NEED ((size_t)(U_GB + 8388608) * 2)   // 67,371,008 B

// packed RNE fp32->bf16 pair via v_perm
__device__ __forceinline__ unsigned pkbf(float a, float b) {
    unsigned ua = __builtin_bit_cast(unsigned, a);
    unsigned ub = __builtin_bit_cast(unsigned, b);
    ua += 0x7fffu + ((ua >> 16) & 1u);
    ub += 0x7fffu + ((ub >> 16) & 1u);
    return __builtin_amdgcn_perm(ub, ua, 0x07060302);
}
__device__ __forceinline__ u16 f2bfu(float f) {
    unsigned u = __builtin_bit_cast(unsigned, f);
    return (u16)((u + 0x7fffu + ((u >> 16) & 1u)) >> 16);
}
__device__ __forceinline__ float bf2f(u16 v) {
    unsigned u = ((unsigned)v) << 16;
    return __builtin_bit_cast(float, u);
}
union bfr { unsigned u[4]; bf16x8 v; };
__device__ __forceinline__ bf16x8 ldcvt8(const float* __restrict__ p) {
    f32x4 a = *(const f32x4*)p; f32x4 b = *(const f32x4*)(p + 4);
    bfr r;
    r.u[0] = pkbf(a[0], a[1]); r.u[1] = pkbf(a[2], a[3]);
    r.u[2] = pkbf(b[0], b[1]); r.u[3] = pkbf(b[2], b[3]);
    return r.v;
}
__device__ __forceinline__ bf16x8 ldcvt8s(const float* __restrict__ p, float sc) {
    f32x4 a = *(const f32x4*)p; f32x4 b = *(const f32x4*)(p + 4);
    bfr r;
    r.u[0] = pkbf(a[0] * sc, a[1] * sc); r.u[1] = pkbf(a[2] * sc, a[3] * sc);
    r.u[2] = pkbf(b[0] * sc, b[1] * sc); r.u[3] = pkbf(b[2] * sc, b[3] * sc);
    return r.v;
}
#define MFMA(a, b, c) __builtin_amdgcn_mfma_f32_16x16x32_bf16((a), (b), (c), 0, 0, 0)

// ===========================================================================
// Kernel 1: weight pre-convert fp32 -> bf16 (scale folded into wq).
// ===========================================================================
__global__ void wconv(const float* __restrict__ wq, const float* __restrict__ wk,
                      const float* __restrict__ wv, const float* __restrict__ wg,
                      const float* __restrict__ wo, u16* __restrict__ ws)
{
    const int i0 = (blockIdx.x * 256 + threadIdx.x) * 8;
    const float qsc = 0.17677669529663687f;   // 1/sqrt(32)
    const float* src; u16* dst; float sc = 1.f;
    if (i0 < 32768) {
        const int e = i0 >> 7, c = i0 & 127;
        src = (e < 128 ? wq + e * CIN : wg + (e - 128) * CIN) + c;
        if (e < 128) sc = qsc;
        dst = ws + U_WQG + i0;
    } else if (i0 < 65536) {
        const int j = i0 - 32768, e = j >> 7, c = j & 127;
        src = (e < 128 ? wk + e * CIN : wv + (e - 128) * CIN) + c;
        dst = ws + U_WKV + j;
    } else {
        const int j = i0 - 65536;
        src = wo + j; dst = ws + U_WWO + j;
    }
    *(bf16x8*)dst = ldcvt8s(src, sc);
}

// ===========================================================================
// Kernel 2: projection GEMM (verbatim R3 — proven 74 us, no spill).
// ===========================================================================
__global__ __launch_bounds__(256, 4) void proj(
    const float* __restrict__ q_x, const float* __restrict__ kv_x,
    const float* __restrict__ bg, u16* __restrict__ ws)
{
    const int t = threadIdx.x, lane = t & 63, w = t >> 6;
    const int mrow = lane & 15, grp = lane >> 4;
    const int koff = grp * 8, rbase = grp * 4;
    const int R0 = blockIdx.x * 64;      // block row base
    const int e0 = w * 64;               // wave out-col base
    const int ysel = blockIdx.y;
    const float* __restrict__ src = ysel ? kv_x : q_x;
    const u16* __restrict__ W = ws + (ysel ? U_WKV : U_WQG);
    const bool vpath = (ysel == 1) && (w >= 2);   // V: unswapped operand order

    const f32x4 zf = {0.f, 0.f, 0.f, 0.f};
    f32x4 acc[4][4];
    #pragma unroll
    for (int mt = 0; mt < 4; ++mt)
        #pragma unroll
        for (int nt = 0; nt < 4; ++nt) acc[mt][nt] = zf;

    if (!vpath) {
        #pragma unroll 1
        for (int ct = 0; ct < 4; ++ct) {
            const int c0 = ct * 32 + koff;
            const bf16x8 bw0 = *(const bf16x8*)(W + (e0 +  0 + mrow) * CIN + c0);
            const bf16x8 bw1 = *(const bf16x8*)(W + (e0 + 16 + mrow) * CIN + c0);
            const bf16x8 bw2 = *(const bf16x8*)(W + (e0 + 32 + mrow) * CIN + c0);
            const bf16x8 bw3 = *(const bf16x8*)(W + (e0 + 48 + mrow) * CIN + c0);
            #pragma unroll
            for (int mt = 0; mt < 4; ++mt) {
                const bf16x8 aX = ldcvt8(src + (size_t)(R0 + mt * 16 + mrow) * CIN + c0);
                acc[mt][0] = MFMA(bw0, aX, acc[mt][0]);   // D[e][row]
                acc[mt][1] = MFMA(bw1, aX, acc[mt][1]);
                acc[mt][2] = MFMA(bw2, aX, acc[mt][2]);
                acc[mt][3] = MFMA(bw3, aX, acc[mt][3]);
            }
        }
    } else {
        #pragma unroll 1
        for (int ct = 0; ct < 4; ++ct) {
            const int c0 = ct * 32 + koff;
            const bf16x8 bw0 = *(const bf16x8*)(W + (e0 +  0 + mrow) * CIN + c0);
            const bf16x8 bw1 = *(const bf16x8*)(W + (e0 + 16 + mrow) * CIN + c0);
            const bf16x8 bw2 = *(const bf16x8*)(W + (e0 + 32 + mrow) * CIN + c0);
            const bf16x8 bw3 = *(const bf16x8*)(W + (e0 + 48 + mrow) * CIN + c0);
            #pragma unroll
            for (int mt = 0; mt < 4; ++mt) {
                const bf16x8 aX = ldcvt8(src + (size_t)(R0 + mt * 16 + mrow) * CIN + c0);
                acc[mt][0] = MFMA(aX, bw0, acc[mt][0]);   // D[row][d]
                acc[mt][1] = MFMA(aX, bw1, acc[mt][1]);
                acc[mt][2] = MFMA(aX, bw2, acc[mt][2]);
                acc[mt][3] = MFMA(aX, bw3, acc[mt][3]);
            }
        }
    }

    if (!ysel) {
        if (w < 2) {
            #pragma unroll
            for (int mt = 0; mt < 4; ++mt) {
                const size_t row = (size_t)(R0 + mt * 16 + mrow);
                #pragma unroll
                for (int nt = 0; nt < 4; ++nt) {
                    uint2 v;
                    v.x = pkbf(acc[mt][nt][0], acc[mt][nt][1]);
                    v.y = pkbf(acc[mt][nt][2], acc[mt][nt][3]);
                    *(uint2*)&ws[U_QB + row * CIN + e0 + nt * 16 + rbase] = v;
                }
            }
        } else {
            #pragma unroll
            for (int mt = 0; mt < 4; ++mt) {
                const size_t row = (size_t)(R0 + mt * 16 + mrow);
                #pragma unroll
                for (int nt = 0; nt < 4; ++nt) {
                    const int eb = (e0 - 128) + nt * 16 + rbase;
                    const f32x4 bgv = *(const f32x4*)(bg + eb);
                    float g[4];
                    #pragma unroll
                    for (int r = 0; r < 4; ++r)
                        g[r] = 1.f / (1.f + __expf(-(acc[mt][nt][r] + bgv[r])));
                    uint2 v;
                    v.x = pkbf(g[0], g[1]);
                    v.y = pkbf(g[2], g[3]);
                    *(uint2*)&ws[U_GB + row * CIN + eb] = v;
                }
            }
        }
    } else {
        if (w < 2) {
            #pragma unroll
            for (int mt = 0; mt < 4; ++mt) {
                const size_t row = (size_t)(R0 + mt * 16 + mrow);
                #pragma unroll
                for (int nt = 0; nt < 4; ++nt) {
                    uint2 v;
                    v.x = pkbf(acc[mt][nt][0], acc[mt][nt][1]);
                    v.y = pkbf(acc[mt][nt][2], acc[mt][nt][3]);
                    *(uint2*)&ws[U_KB + row * CIN + e0 + nt * 16 + rbase] = v;
                }
            }
        } else {
            const int n = R0 >> 8;
            #pragma unroll
            for (int mt = 0; mt < 4; ++mt) {
                const int k0 = (R0 & 255) + mt * 16 + rbase;
                #pragma unroll
                for (int nt = 0; nt < 4; ++nt) {
                    const int d = (e0 - 128) + nt * 16 + mrow;
                    uint2 v;
                    v.x = pkbf(acc[mt][nt][0], acc[mt][nt][1]);
                    v.y = pkbf(acc[mt][nt][2], acc[mt][nt][3]);
                    *(uint2*)&ws[U_VT + ((size_t)n * 128 + d) * 256 + k0] = v;
                }
            }
        }
    }
}

// ===========================================================================
// Kernel 3: flash attention per (h, n) — SWAPPED-OPERAND layout.
// QK^T: s = MFMA(bk, aq) -> reg r <-> k = kb+rbase+r, lane mrow <-> q.
//   * tri bias becomes contiguous f32x4 per lane (natural [q][k] layout!):
//     8 vector loads/kt vs 32 scalar (4x fewer VMEM transactions — this was
//     the dominant cost: 16 segments per scalar load instruction).
//   * mask: float4 loads over k.
//   * P store to LDS: 8 uint2/kt vs 32 scalar u16.
// PV: oa = MFMA(bv, pa) -> reg r <-> d, lane mrow <-> q.
//   * softmax denominator is scalar/lane (q=mrow): 2 shfl_xor vs 16, and
//     aligns with oa with NO redistribution.
//   * gate load + gated-O store: uint2 (bf16 x4 over d).
// Gated O (bf16) overwrites the Q slab (own h columns only — disjoint per h).
// fp32 `out` is NOT written here; gout produces it from bf16 gated-O.
// ===========================================================================
#define PST 40   // LDS P-tile row stride (u16): 80 B
__global__ __launch_bounds__(256, 4) void flash(
    u16* __restrict__ ws, const float* __restrict__ mask_bias,
    const float* __restrict__ tri_bias)
{
    const int h = blockIdx.x, n = blockIdx.y;
    const int t = threadIdx.x, lane = t & 63, w = t >> 6;
    const int mrow = lane & 15, grp = lane >> 4;
    const int koff = grp * 8, rbase = grp * 4;
    const int q0 = w * 64;

    __shared__ u16 Pt[4 * 64 * PST];   // 20480 B, per-wave [64 q][32 k] tile
    __shared__ float msk[NRES];

    if (t < 64) *(float4*)&msk[t * 4] = *(const float4*)(mask_bias + n * NRES + t * 4);

    u16* __restrict__ QOg = ws + U_QB + (size_t)n * NRES * CIN;   // Q in, gated-O out
    const u16* __restrict__ Kb = ws + U_KB + (size_t)n * NRES * CIN;
    const u16* __restrict__ Vt = ws + U_VT + (size_t)n * 128 * 256;
    const u16* __restrict__ Gb = ws + U_GB + (size_t)n * NRES * CIN;
    const float* __restrict__ trih = tri_bias + (size_t)h * NRES * NRES;

    bf16x8 aq[4];
    #pragma unroll
    for (int qt = 0; qt < 4; ++qt)
        aq[qt] = *(const bf16x8*)(QOg + (size_t)(q0 + qt * 16 + mrow) * CIN + h * DH + koff);
    __syncthreads();   // msk visible

    const f32x4 zf = {0.f, 0.f, 0.f, 0.f};
    f32x4 oa[4][2];
    float ls[4];
    #pragma unroll
    for (int qt = 0; qt < 4; ++qt) { oa[qt][0] = zf; oa[qt][1] = zf; ls[qt] = 0.f; }

    u16* __restrict__ pw = &Pt[w * 64 * PST];

    for (int kt = 0; kt < 8; ++kt) {
        const int kb = kt * 32;
        // K fragments (A-operand): 16 k-rows each
        bf16x8 bk0 = *(const bf16x8*)(Kb + (size_t)(kb + mrow) * CIN + h * DH + koff);
        bf16x8 bk1 = *(const bf16x8*)(Kb + (size_t)(kb + 16 + mrow) * CIN + h * DH + koff);
        // V^T fragments (A-operand): 16 d-rows each
        bf16x8 bv0 = *(const bf16x8*)(Vt + (size_t)(h * DH + mrow) * NRES + kb + koff);
        bf16x8 bv1 = *(const bf16x8*)(Vt + (size_t)(h * DH + 16 + mrow) * NRES + kb + koff);
        // mask over this lane's k-slots
        const f32x4 m0 = *(const f32x4*)&msk[kb + rbase];
        const f32x4 m1 = *(const f32x4*)&msk[kb + 16 + rbase];

        #pragma unroll
        for (int qt = 0; qt < 4; ++qt) {
            const int q = q0 + qt * 16 + mrow;
            // tri bias: contiguous f32x4 per lane in natural [q][k] layout
            const f32x4 t0 = *(const f32x4*)(trih + (size_t)q * NRES + kb + rbase);
            const f32x4 t1 = *(const f32x4*)(trih + (size_t)q * NRES + kb + 16 + rbase);
            f32x4 s0 = MFMA(bk0, aq[qt], zf);   // r <-> k=kb+rbase+r, mrow <-> q
            f32x4 s1 = MFMA(bk1, aq[qt], zf);   // r <-> k=kb+16+rbase+r
            float part = 0.f;
            #pragma unroll
            for (int r = 0; r < 4; ++r) {
                s0[r] = __expf(s0[r] + t0[r] + m0[r] - 8.f);
                s1[r] = __expf(s1[r] + t1[r] + m1[r] - 8.f);
                part += s0[r] + s1[r];
            }
            ls[qt] += part;
            uint2 v0, v1;
            v0.x = pkbf(s0[0], s0[1]); v0.y = pkbf(s0[2], s0[3]);
            v1.x = pkbf(s1[0], s1[1]); v1.y = pkbf(s1[2], s1[3]);
            *(uint2*)&pw[(qt * 16 + mrow) * PST + rbase]      = v0;
            *(uint2*)&pw[(qt * 16 + mrow) * PST + 16 + rbase] = v1;
        }
        asm volatile("s_waitcnt lgkmcnt(0)" ::: "memory");   // P writes landed
        __builtin_amdgcn_sched_barrier(0);                   // don't hoist MFMAs above
        #pragma unroll
        for (int qt = 0; qt < 4; ++qt) {
            bf16x8 pa = *(const bf16x8*)&pw[(qt * 16 + mrow) * PST + koff];
            oa[qt][0] = MFMA(bv0, pa, oa[qt][0]);   // r <-> d=rbase+r, mrow <-> q
            oa[qt][1] = MFMA(bv1, pa, oa[qt][1]);   // r <-> d=16+rbase+r
        }
    }

    // epilogue: normalize + gate, store gated O (bf16) over the Q slab.
    // ls is per-lane scalar with q = mrow — matches oa's q coordinate exactly.
    #pragma unroll
    for (int qt = 0; qt < 4; ++qt) {
        float lv = ls[qt];
        lv += __shfl_xor(lv, 16, 64);
        lv += __shfl_xor(lv, 32, 64);
        const float inv = 1.f / lv;
        const int q = q0 + qt * 16 + mrow;
        #pragma unroll
        for (int half = 0; half < 2; ++half) {
            const size_t off = (size_t)q * CIN + h * DH + half * 16 + rbase;
            const uint2 gv = *(const uint2*)&Gb[off];
            const float g0 = bf2f((u16)(gv.x)),        g1 = bf2f((u16)(gv.x >> 16));
            const float g2 = bf2f((u16)(gv.y)),        g3 = bf2f((u16)(gv.y >> 16));
            uint2 ov;
            ov.x = pkbf(oa[qt][half][0] * inv * g0, oa[qt][half][1] * inv * g1);
            ov.y = pkbf(oa[qt][half][2] * inv * g2, oa[qt][half][3] * inv * g3);
            *(uint2*)&QOg[off] = ov;
        }
    }
}

// ===========================================================================
// Kernel 4: output projection. out = gatedO(bf16, in ws) * Wo^T + bo -> fp32.
// Swapped MFMA: reg r <-> c (contiguous) -> f32x4 output stores; bf16 input
// (no fp32 round-trip, no convert).
// ===========================================================================
__global__ __launch_bounds__(256, 4) void gout(
    const u16* __restrict__ ws, const float* __restrict__ bo,
    float* __restrict__ out)
{
    const int t = threadIdx.x, lane = t & 63, w = t >> 6;
    const int mrow = lane & 15, grp = lane >> 4;
    const int koff = grp * 8, rbase = grp * 4;
    const int r0 = blockIdx.x * 128 + w * 32;
    const u16* __restrict__ Wo = ws + U_WWO;
    const u16* __restrict__ QOg = ws + U_QB;

    const f32x4 zf = {0.f, 0.f, 0.f, 0.f};
    f32x4 acc[2][8];
    #pragma unroll
    for (int at = 0; at < 2; ++at)
        #pragma unroll
        for (int nt = 0; nt < 8; ++nt) acc[at][nt] = zf;

    #pragma unroll
    for (int ks = 0; ks < 4; ++ks) {
        const int e0 = ks * 32 + koff;
        const bf16x8 a0 = *(const bf16x8*)(QOg + (size_t)(r0 + mrow) * CIN + e0);
        const bf16x8 a1 = *(const bf16x8*)(QOg + (size_t)(r0 + 16 + mrow) * CIN + e0);
        #pragma unroll
        for (int nt = 0; nt < 8; ++nt) {
            const bf16x8 bw = *(const bf16x8*)(Wo + (nt * 16 + mrow) * CIN + e0);
            acc[0][nt] = MFMA(bw, a0, acc[0][nt]);   // r <-> c=nt*16+rbase+r, mrow <-> row
            acc[1][nt] = MFMA(bw, a1, acc[1][nt]);
        }
    }

    #pragma unroll
    for (int nt = 0; nt < 8; ++nt) {
        const f32x4 bov = *(const f32x4*)&bo[nt * 16 + rbase];
        #pragma unroll
        for (int at = 0; at < 2; ++at) {
            const f32x4 v = acc[at][nt] + bov;
            *(f32x4*)&out[(size_t)(r0 + at * 16 + mrow) * CIN + nt * 16 + rbase] = v;
        }
    }
}

// ===========================================================================
// Fallback path (proven correct) for small ws_size.
// ===========================================================================
#define KST 32
#define VST 264
#define GST 136

__global__ __launch_bounds__(256, 3) void attn_fb(
    const float* __restrict__ q_x, const float* __restrict__ kv_x,
    const float* __restrict__ mask_bias, const float* __restrict__ tri_bias,
    const float* __restrict__ wq, const float* __restrict__ wk,
    const float* __restrict__ wv, float* __restrict__ o_out)
{
    const int h = blockIdx.x, n = blockIdx.y;
    const int t = threadIdx.x;
    const int lane = t & 63, w = t >> 6;
    const int mrow = lane & 15;
    const int grp  = lane >> 4;
    const int koff = grp * 8;
    const int rbase = grp * 4;
    const int q0 = w * 64;

    __shared__ u16 Ks[NRES * KST];
    __shared__ u16 Vt[DH * VST];
    __shared__ u16 Ptb[4 * 32 * PST];
    __shared__ float msk[NRES];

    if (t < 64) *(float4*)&msk[t * 4] = *(const float4*)(mask_bias + n * NRES + t * 4);

    const float* __restrict__ qxn = q_x  + (size_t)n * NRES * CIN;
    const float* __restrict__ kxn = kv_x + (size_t)n * NRES * CIN;
    const float* __restrict__ wqh = wq + h * DH * CIN;
    const float* __restrict__ wkh = wk + h * DH * CIN;
    const float* __restrict__ wvh = wv + h * DH * CIN;

    f32x4 aq_[4][2], ak_[4][2], av_[4][2];
    const f32x4 zf = {0.f, 0.f, 0.f, 0.f};
    #pragma unroll
    for (int qt = 0; qt < 4; ++qt)
        #pragma unroll
        for (int dt = 0; dt < 2; ++dt) { aq_[qt][dt] = zf; ak_[qt][dt] = zf; av_[qt][dt] = zf; }

    const float qsc = 0.17677669529663687f;
    #pragma unroll
    for (int ct = 0; ct < 4; ++ct) {
        const int c0 = ct * 32 + koff;
        bf16x8 bq0 = ldcvt8s(wqh + mrow * CIN + c0, qsc);
        bf16x8 bq1 = ldcvt8s(wqh + (16 + mrow) * CIN + c0, qsc);
        bf16x8 bk0 = ldcvt8(wkh + mrow * CIN + c0);
        bf16x8 bk1 = ldcvt8(wkh + (16 + mrow) * CIN + c0);
        bf16x8 bv0 = ldcvt8(wvh + mrow * CIN + c0);
        bf16x8 bv1 = ldcvt8(wvh + (16 + mrow) * CIN + c0);
        #pragma unroll
        for (int qt = 0; qt < 4; ++qt) {
            bf16x8 aX = ldcvt8(qxn + (q0 + qt * 16 + mrow) * CIN + c0);
            aq_[qt][0] = MFMA(aX, bq0, aq_[qt][0]);
            aq_[qt][1] = MFMA(aX, bq1, aq_[qt][1]);
            bf16x8 aK = ldcvt8(kxn + (q0 + qt * 16 + mrow) * CIN + c0);
            ak_[qt][0] = MFMA(aK, bk0, ak_[qt][0]);
            ak_[qt][1] = MFMA(aK, bk1, ak_[qt][1]);
            av_[qt][0] = MFMA(aK, bv0, av_[qt][0]);
            av_[qt][1] = MFMA(aK, bv1, av_[qt][1]);
        }
    }

    #pragma unroll
    for (int qt = 0; qt < 4; ++qt)
        #pragma unroll
        for (int dt = 0; dt < 2; ++dt)
            #pragma unroll
            for (int r = 0; r < 4; ++r) {
                const int row = q0 + qt * 16 + rbase + r;
                const int d = dt * 16 + mrow;
                Ks[row * KST + d] = f2bfu(ak_[qt][dt][r]);
                Vt[d * VST + row] = f2bfu(av_[qt][dt][r]);
            }

    u16* __restrict__ pw = &Ptb[w * 32 * PST];
    bf16x8 aq[4];
    #pragma unroll
    for (int h2 = 0; h2 < 2; ++h2) {
        #pragma unroll
        for (int j = 0; j < 2; ++j) {
            const int qt = h2 * 2 + j;
            #pragma unroll
            for (int dt = 0; dt < 2; ++dt)
                #pragma unroll
                for (int r = 0; r < 4; ++r)
                    pw[(j * 16 + rbase + r) * PST + dt * 16 + mrow] = f2bfu(aq_[qt][dt][r]);
        }
        asm volatile("s_waitcnt lgkmcnt(0)" ::: "memory");
        #pragma unroll
        for (int j = 0; j < 2; ++j)
            aq[h2 * 2 + j] = *(const bf16x8*)&pw[(j * 16 + mrow) * PST + koff];
        asm volatile("s_waitcnt lgkmcnt(0)" ::: "memory");
    }
    __syncthreads();

    f32x4 oa[4][2], ls4[4];
    #pragma unroll
    for (int qt = 0; qt < 4; ++qt) { oa[qt][0] = zf; oa[qt][1] = zf; ls4[qt] = zf; }

    const float* __restrict__ trih = tri_bias + (size_t)h * NRES * NRES;

    for (int kt = 0; kt < 8; ++kt) {
        const int kb = kt * 32;
        bf16x8 bk0 = *(const bf16x8*)&Ks[(kb + mrow) * KST + koff];
        bf16x8 bk1 = *(const bf16x8*)&Ks[(kb + 16 + mrow) * KST + koff];
        bf16x8 bv0 = *(const bf16x8*)&Vt[mrow * VST + kb + koff];
        bf16x8 bv1 = *(const bf16x8*)&Vt[(16 + mrow) * VST + kb + koff];
        const float mb0 = msk[kb + mrow] - 8.f;
        const float mb1 = msk[kb + 16 + mrow] - 8.f;

        #pragma unroll
        for (int h2 = 0; h2 < 2; ++h2) {
            float tr0[2][4], tr1[2][4];
            #pragma unroll
            for (int j = 0; j < 2; ++j) {
                const int qt = h2 * 2 + j;
                const float* __restrict__ trow =
                    trih + (q0 + qt * 16 + rbase) * NRES + kb + mrow;
                #pragma unroll
                for (int r = 0; r < 4; ++r) {
                    tr0[j][r] = trow[r * NRES];
                    tr1[j][r] = trow[r * NRES + 16];
                }
            }
            #pragma unroll
            for (int j = 0; j < 2; ++j) {
                const int qt = h2 * 2 + j;
                f32x4 s0 = MFMA(aq[qt], bk0, zf);
                f32x4 s1 = MFMA(aq[qt], bk1, zf);
                #pragma unroll
                for (int r = 0; r < 4; ++r) {
                    s0[r] = __expf(s0[r] + tr0[j][r] + mb0);
                    s1[r] = __expf(s1[r] + tr1[j][r] + mb1);
                }
                ls4[qt] += s0 + s1;
                #pragma unroll
                for (int r = 0; r < 4; ++r) {
                    pw[(j * 16 + rbase + r) * PST + mrow]      = f2bfu(s0[r]);
                    pw[(j * 16 + rbase + r) * PST + 16 + mrow] = f2bfu(s1[r]);
                }
            }
            asm volatile("s_waitcnt lgkmcnt(0)" ::: "memory");
            #pragma unroll
            for (int j = 0; j < 2; ++j) {
                const int qt = h2 * 2 + j;
                bf16x8 pa = *(const bf16x8*)&pw[(j * 16 + mrow) * PST + koff];
                oa[qt][0] = MFMA(pa, bv0, oa[qt][0]);
                oa[qt][1] = MFMA(pa, bv1, oa[qt][1]);
            }
        }
    }

    float* __restrict__ orow = o_out + (size_t)n * NRES * CIN + h * DH;
    #pragma unroll
    for (int qt = 0; qt < 4; ++qt) {
        f32x4 lv = ls4[qt];
        #pragma unroll
        for (int xm = 1; xm < 16; xm <<= 1) {
            lv[0] += __shfl_xor(lv[0], xm, 64);
            lv[1] += __shfl_xor(lv[1], xm, 64);
            lv[2] += __shfl_xor(lv[2], xm, 64);
            lv[3] += __shfl_xor(lv[3], xm, 64);
        }
        #pragma unroll
        for (int r = 0; r < 4; ++r) {
            const float inv = 1.f / lv[r];
            const int q = q0 + qt * 16 + rbase + r;
            orow[q * CIN + mrow]      = oa[qt][0][r] * inv;
            orow[q * CIN + 16 + mrow] = oa[qt][1][r] * inv;
        }
    }
}

__global__ __launch_bounds__(256, 4) void gate_fb(
    const float* __restrict__ q_x, const float* __restrict__ wg,
    const float* __restrict__ bg, const float* __restrict__ wo,
    const float* __restrict__ bo, float* io)
{
    const int t = threadIdx.x;
    const int lane = t & 63, w = t >> 6;
    const int mrow = lane & 15, grp = lane >> 4;
    const int koff = grp * 8, rbase = grp * 4;
    const int r0 = blockIdx.x * 128 + w * 32;

    __shared__ u16 Gt[4 * 32 * GST];
    u16* __restrict__ gw = &Gt[w * 32 * GST];

    const f32x4 zf = {0.f, 0.f, 0.f, 0.f};
    f32x4 acc[2][8];
    #pragma unroll
    for (int at = 0; at < 2; ++at)
        #pragma unroll
        for (int nt = 0; nt < 8; ++nt) acc[at][nt] = zf;

    #pragma unroll
    for (int ks = 0; ks < 4; ++ks) {
        const int c0 = ks * 32 + koff;
        bf16x8 ax0 = ldcvt8(q_x + (size_t)(r0 + mrow) * CIN + c0);
        bf16x8 ax1 = ldcvt8(q_x + (size_t)(r0 + 16 + mrow) * CIN + c0);
        #pragma unroll
        for (int nt = 0; nt < 8; ++nt) {
            bf16x8 bw = ldcvt8(wg + (nt * 16 + mrow) * CIN + c0);
            acc[0][nt] = MFMA(ax0, bw, acc[0][nt]);
            acc[1][nt] = MFMA(ax1, bw, acc[1][nt]);
        }
    }

    #pragma unroll
    for (int nt = 0; nt < 8; ++nt) {
        const float bge = bg[nt * 16 + mrow];
        #pragma unroll
        for (int at = 0; at < 2; ++at)
            #pragma unroll
            for (int r = 0; r < 4; ++r) {
                const int qg = r0 + at * 16 + rbase + r;
                const float ov = io[(size_t)qg * CIN + nt * 16 + mrow];
                const float g = 1.f / (1.f + __expf(-(acc[at][nt][r] + bge)));
                gw[(at * 16 + rbase + r) * GST + nt * 16 + mrow] = f2bfu(ov * g);
            }
    }
    asm volatile("s_waitcnt lgkmcnt(0)" ::: "memory");

    f32x4 acc2[2][8];
    #pragma unroll
    for (int at = 0; at < 2; ++at)
        #pragma unroll
        for (int nt = 0; nt < 8; ++nt) acc2[at][nt] = zf;

    #pragma unroll
    for (int ks = 0; ks < 4; ++ks) {
        const int e0 = ks * 32 + koff;
        bf16x8 ag0 = *(const bf16x8*)&gw[mrow * GST + e0];
        bf16x8 ag1 = *(const bf16x8*)&gw[(16 + mrow) * GST + e0];
        #pragma unroll
        for (int nt = 0; nt < 8; ++nt) {
            bf16x8 bw = ldcvt8(wo + (nt * 16 + mrow) * CIN + e0);
            acc2[0][nt] = MFMA(ag0, bw, acc2[0][nt]);
            acc2[1][nt] = MFMA(ag1, bw, acc2[1][nt]);
        }
    }

    #pragma unroll
    for (int nt = 0; nt < 8; ++nt) {
        const float boc = bo[nt * 16 + mrow];
        #pragma unroll
        for (int at = 0; at < 2; ++at)
            #pragma unroll
            for (int r = 0; r < 4; ++r)
                io[(size_t)(r0 + at * 16 + rbase + r) * CIN + nt * 16 + mrow] =
                    acc2[at][nt][r] + boc;
    }
}

extern "C" void kernel_launch(void* const* d_in, const int* in_sizes, int n_in,
                              void* d_out, int out_size, void* d_ws, size_t ws_size,
                              hipStream_t stream) {
    const float* q_x  = (const float*)d_in[0];
    const float* kv_x = (const float*)d_in[1];
    const float* mask = (const float*)d_in[2];
    const float* tri  = (const float*)d_in[3];
    const float* wq   = (const float*)d_in[4];
    const float* wk   = (const float*)d_in[5];
    const float* wv   = (const float*)d_in[6];
    const float* wg   = (const float*)d_in[7];
    const float* bg   = (const float*)d_in[8];
    const float* wo   = (const float*)d_in[9];
    const float* bo   = (const float*)d_in[10];
    float* out = (float*)d_out;

    if (ws_size >= WS_NEED) {
        u16* ws16 = (u16*)d_ws;
        wconv<<<40, 256, 0, stream>>>(wq, wk, wv, wg, wo, ws16);
        proj<<<dim3(1024, 2), 256, 0, stream>>>(q_x, kv_x, bg, ws16);
        flash<<<dim3(NH, NRES), 256, 0, stream>>>(ws16, mask, tri);
        gout<<<512, 256, 0, stream>>>(ws16, bo, out);
    } else {
        attn_fb<<<dim3(NH, NRES), 256, 0, stream>>>(q_x, kv_x, mask, tri, wq, wk, wv, out);
        gate_fb<<<(NRES * NRES) / 128, 256, 0, stream>>>(q_x, wg, bg, wo, bo, out);
    }
}

// Round 6
// 225.388 us; speedup vs baseline: 1.2052x; 1.0962x over previous
//
#include <hip/hip_runtime.h>

#define NRES 256
#define CIN  128
#define NH   4
#define DH   32

typedef __attribute__((ext_vector_type(4))) float f32x4;
typedef __attribute__((ext_vector_type(8))) short bf16x8;
typedef unsigned short u16;

// ---- ws layout (u16 units) ----
#define U_WQG 0                      // [256][128] bf16: rows 0-127 = wq*qsc, 128-255 = wg
#define U_WKV 32768                  // [256][128] bf16: rows 0-127 = wk, 128-255 = wv
#define U_WWO 65536                  // [128][128] bf16: wo[c][e]
#define U_QB  131072                 // [65536][128] bf16 scaled-Q (reused as gated-O)
#define U_KB  (U_QB + 8388608)       // [65536][128] bf16 K
#define U_VT  (U_KB + 8388608)       // [256 n][128 d][256 k] bf16 V^T
#define U_GB  (U_VT + 8388608)       // [65536][128] bf16 sigmoid gate
#define WS_NEED ((size_t)(U_GB + 8388608) * 2)   // 67,371,008 B

// packed RNE fp32->bf16 pair via v_perm
__device__ __forceinline__ unsigned pkbf(float a, float b) {
    unsigned ua = __builtin_bit_cast(unsigned, a);
    unsigned ub = __builtin_bit_cast(unsigned, b);
    ua += 0x7fffu + ((ua >> 16) & 1u);
    ub += 0x7fffu + ((ub >> 16) & 1u);
    return __builtin_amdgcn_perm(ub, ua, 0x07060302);
}
__device__ __forceinline__ u16 f2bfu(float f) {
    unsigned u = __builtin_bit_cast(unsigned, f);
    return (u16)((u + 0x7fffu + ((u >> 16) & 1u)) >> 16);
}
__device__ __forceinline__ float bf2f(u16 v) {
    unsigned u = ((unsigned)v) << 16;
    return __builtin_bit_cast(float, u);
}
union bfr { unsigned u[4]; bf16x8 v; };
__device__ __forceinline__ bf16x8 ldcvt8(const float* __restrict__ p) {
    f32x4 a = *(const f32x4*)p; f32x4 b = *(const f32x4*)(p + 4);
    bfr r;
    r.u[0] = pkbf(a[0], a[1]); r.u[1] = pkbf(a[2], a[3]);
    r.u[2] = pkbf(b[0], b[1]); r.u[3] = pkbf(b[2], b[3]);
    return r.v;
}
__device__ __forceinline__ bf16x8 ldcvt8s(const float* __restrict__ p, float sc) {
    f32x4 a = *(const f32x4*)p; f32x4 b = *(const f32x4*)(p + 4);
    bfr r;
    r.u[0] = pkbf(a[0] * sc, a[1] * sc); r.u[1] = pkbf(a[2] * sc, a[3] * sc);
    r.u[2] = pkbf(b[0] * sc, b[1] * sc); r.u[3] = pkbf(b[2] * sc, b[3] * sc);
    return r.v;
}
#define MFMA(a, b, c) __builtin_amdgcn_mfma_f32_16x16x32_bf16((a), (b), (c), 0, 0, 0)

// ===========================================================================
// Kernel 1: weight pre-convert fp32 -> bf16 (scale folded into wq).
// ===========================================================================
__global__ void wconv(const float* __restrict__ wq, const float* __restrict__ wk,
                      const float* __restrict__ wv, const float* __restrict__ wg,
                      const float* __restrict__ wo, u16* __restrict__ ws)
{
    const int i0 = (blockIdx.x * 256 + threadIdx.x) * 8;
    const float qsc = 0.17677669529663687f;   // 1/sqrt(32)
    const float* src; u16* dst; float sc = 1.f;
    if (i0 < 32768) {
        const int e = i0 >> 7, c = i0 & 127;
        src = (e < 128 ? wq + e * CIN : wg + (e - 128) * CIN) + c;
        if (e < 128) sc = qsc;
        dst = ws + U_WQG + i0;
    } else if (i0 < 65536) {
        const int j = i0 - 32768, e = j >> 7, c = j & 127;
        src = (e < 128 ? wk + e * CIN : wv + (e - 128) * CIN) + c;
        dst = ws + U_WKV + j;
    } else {
        const int j = i0 - 65536;
        src = wo + j; dst = ws + U_WWO + j;
    }
    *(bf16x8*)dst = ldcvt8s(src, sc);
}

// ===========================================================================
// Kernel 2: projection GEMM v2 — LDS A-staging + 2-deep W prefetch.
// grid (1024,2); block = 64 rows x 256 outs (4 waves, wave = 64x64 tile).
// Changes vs R3 (which measured 74.5 us, all pipes idle -> VMEM delivery /
// latency-chain bound):
//  * A-tile (64x128) converted to bf16 ONCE into LDS (As, stride 136 u16 to
//    break bank aliasing) -> per-block A L1 traffic 128KB -> 32KB, per-wave
//    global loads 48 -> 24.
//  * W fragments double-buffered across the unroll-1 ct loop: next ct's 4
//    loads issue BEFORE current ct's MFMAs -> W latency hidden.
//  * launch_bounds(256,3): VGPR cap ~170, live ~120 (acc64+bw16+nbw16+ax16)
//    -> no spill (R2 lesson: spill shows as FETCH/WRITE blowup; watch it).
// Store/index math verbatim from R3 (proven absmax 1.22e-4).
// ===========================================================================
#define AST 136   // As row stride (u16): 272 B, 16B-aligned, breaks bank alias
__global__ __launch_bounds__(256, 3) void proj(
    const float* __restrict__ q_x, const float* __restrict__ kv_x,
    const float* __restrict__ bg, u16* __restrict__ ws)
{
    const int t = threadIdx.x, lane = t & 63, w = t >> 6;
    const int mrow = lane & 15, grp = lane >> 4;
    const int koff = grp * 8, rbase = grp * 4;
    const int R0 = blockIdx.x * 64;      // block row base
    const int e0 = w * 64;               // wave out-col base
    const int ysel = blockIdx.y;
    const float* __restrict__ src = ysel ? kv_x : q_x;
    const u16* __restrict__ W = ws + (ysel ? U_WKV : U_WQG);
    const bool vpath = (ysel == 1) && (w >= 2);   // V: unswapped operand order

    __shared__ u16 As[64 * AST];   // 17408 B: 64-row bf16 A tile

    // ---- stage A: wave w converts rows w*16..w*16+15, grp picks 32-col band
    {
        const int srow = w * 16 + mrow;
        const float* __restrict__ sp = src + (size_t)(R0 + srow) * CIN + grp * 32;
        u16* __restrict__ dp = &As[srow * AST + grp * 32];
        #pragma unroll
        for (int cc = 0; cc < 4; ++cc)
            *(bf16x8*)(dp + cc * 8) = ldcvt8(sp + cc * 8);
    }

    const f32x4 zf = {0.f, 0.f, 0.f, 0.f};
    f32x4 acc[4][4];
    #pragma unroll
    for (int mt = 0; mt < 4; ++mt)
        #pragma unroll
        for (int nt = 0; nt < 4; ++nt) acc[mt][nt] = zf;

    // preload W fragments for ct=0 (independent of LDS; overlaps barrier)
    bf16x8 bw0 = *(const bf16x8*)(W + (e0 +  0 + mrow) * CIN + koff);
    bf16x8 bw1 = *(const bf16x8*)(W + (e0 + 16 + mrow) * CIN + koff);
    bf16x8 bw2 = *(const bf16x8*)(W + (e0 + 32 + mrow) * CIN + koff);
    bf16x8 bw3 = *(const bf16x8*)(W + (e0 + 48 + mrow) * CIN + koff);

    __syncthreads();   // As visible

    if (!vpath) {
        #pragma unroll 1
        for (int ct = 0; ct < 4; ++ct) {
            // prefetch next ct's W (wraps to ct=0 addresses on last iter; harmless)
            const int c0n = ((ct + 1) & 3) * 32 + koff;
            const bf16x8 nb0 = *(const bf16x8*)(W + (e0 +  0 + mrow) * CIN + c0n);
            const bf16x8 nb1 = *(const bf16x8*)(W + (e0 + 16 + mrow) * CIN + c0n);
            const bf16x8 nb2 = *(const bf16x8*)(W + (e0 + 32 + mrow) * CIN + c0n);
            const bf16x8 nb3 = *(const bf16x8*)(W + (e0 + 48 + mrow) * CIN + c0n);
            const int c0 = ct * 32 + koff;
            #pragma unroll
            for (int mt = 0; mt < 4; ++mt) {
                const bf16x8 aX = *(const bf16x8*)&As[(mt * 16 + mrow) * AST + c0];
                acc[mt][0] = MFMA(bw0, aX, acc[mt][0]);   // D[e][row]
                acc[mt][1] = MFMA(bw1, aX, acc[mt][1]);
                acc[mt][2] = MFMA(bw2, aX, acc[mt][2]);
                acc[mt][3] = MFMA(bw3, aX, acc[mt][3]);
            }
            bw0 = nb0; bw1 = nb1; bw2 = nb2; bw3 = nb3;
        }
    } else {
        #pragma unroll 1
        for (int ct = 0; ct < 4; ++ct) {
            const int c0n = ((ct + 1) & 3) * 32 + koff;
            const bf16x8 nb0 = *(const bf16x8*)(W + (e0 +  0 + mrow) * CIN + c0n);
            const bf16x8 nb1 = *(const bf16x8*)(W + (e0 + 16 + mrow) * CIN + c0n);
            const bf16x8 nb2 = *(const bf16x8*)(W + (e0 + 32 + mrow) * CIN + c0n);
            const bf16x8 nb3 = *(const bf16x8*)(W + (e0 + 48 + mrow) * CIN + c0n);
            const int c0 = ct * 32 + koff;
            #pragma unroll
            for (int mt = 0; mt < 4; ++mt) {
                const bf16x8 aX = *(const bf16x8*)&As[(mt * 16 + mrow) * AST + c0];
                acc[mt][0] = MFMA(aX, bw0, acc[mt][0]);   // D[row][d]
                acc[mt][1] = MFMA(aX, bw1, acc[mt][1]);
                acc[mt][2] = MFMA(aX, bw2, acc[mt][2]);
                acc[mt][3] = MFMA(aX, bw3, acc[mt][3]);
            }
            bw0 = nb0; bw1 = nb1; bw2 = nb2; bw3 = nb3;
        }
    }

    if (!ysel) {
        if (w < 2) {
            #pragma unroll
            for (int mt = 0; mt < 4; ++mt) {
                const size_t row = (size_t)(R0 + mt * 16 + mrow);
                #pragma unroll
                for (int nt = 0; nt < 4; ++nt) {
                    uint2 v;
                    v.x = pkbf(acc[mt][nt][0], acc[mt][nt][1]);
                    v.y = pkbf(acc[mt][nt][2], acc[mt][nt][3]);
                    *(uint2*)&ws[U_QB + row * CIN + e0 + nt * 16 + rbase] = v;
                }
            }
        } else {
            #pragma unroll
            for (int mt = 0; mt < 4; ++mt) {
                const size_t row = (size_t)(R0 + mt * 16 + mrow);
                #pragma unroll
                for (int nt = 0; nt < 4; ++nt) {
                    const int eb = (e0 - 128) + nt * 16 + rbase;
                    const f32x4 bgv = *(const f32x4*)(bg + eb);
                    float g[4];
                    #pragma unroll
                    for (int r = 0; r < 4; ++r)
                        g[r] = 1.f / (1.f + __expf(-(acc[mt][nt][r] + bgv[r])));
                    uint2 v;
                    v.x = pkbf(g[0], g[1]);
                    v.y = pkbf(g[2], g[3]);
                    *(uint2*)&ws[U_GB + row * CIN + eb] = v;
                }
            }
        }
    } else {
        if (w < 2) {
            #pragma unroll
            for (int mt = 0; mt < 4; ++mt) {
                const size_t row = (size_t)(R0 + mt * 16 + mrow);
                #pragma unroll
                for (int nt = 0; nt < 4; ++nt) {
                    uint2 v;
                    v.x = pkbf(acc[mt][nt][0], acc[mt][nt][1]);
                    v.y = pkbf(acc[mt][nt][2], acc[mt][nt][3]);
                    *(uint2*)&ws[U_KB + row * CIN + e0 + nt * 16 + rbase] = v;
                }
            }
        } else {
            const int n = R0 >> 8;
            #pragma unroll
            for (int mt = 0; mt < 4; ++mt) {
                const int k0 = (R0 & 255) + mt * 16 + rbase;
                #pragma unroll
                for (int nt = 0; nt < 4; ++nt) {
                    const int d = (e0 - 128) + nt * 16 + mrow;
                    uint2 v;
                    v.x = pkbf(acc[mt][nt][0], acc[mt][nt][1]);
                    v.y = pkbf(acc[mt][nt][2], acc[mt][nt][3]);
                    *(uint2*)&ws[U_VT + ((size_t)n * 128 + d) * 256 + k0] = v;
                }
            }
        }
    }
}

// ===========================================================================
// Kernel 3: flash attention per (h, n) — swapped-operand layout (R5, kept).
// ===========================================================================
#define PST 40   // LDS P-tile row stride (u16): 80 B
__global__ __launch_bounds__(256, 4) void flash(
    u16* __restrict__ ws, const float* __restrict__ mask_bias,
    const float* __restrict__ tri_bias)
{
    const int h = blockIdx.x, n = blockIdx.y;
    const int t = threadIdx.x, lane = t & 63, w = t >> 6;
    const int mrow = lane & 15, grp = lane >> 4;
    const int koff = grp * 8, rbase = grp * 4;
    const int q0 = w * 64;

    __shared__ u16 Pt[4 * 64 * PST];   // 20480 B, per-wave [64 q][32 k] tile
    __shared__ float msk[NRES];

    if (t < 64) *(float4*)&msk[t * 4] = *(const float4*)(mask_bias + n * NRES + t * 4);

    u16* __restrict__ QOg = ws + U_QB + (size_t)n * NRES * CIN;   // Q in, gated-O out
    const u16* __restrict__ Kb = ws + U_KB + (size_t)n * NRES * CIN;
    const u16* __restrict__ Vt = ws + U_VT + (size_t)n * 128 * 256;
    const u16* __restrict__ Gb = ws + U_GB + (size_t)n * NRES * CIN;
    const float* __restrict__ trih = tri_bias + (size_t)h * NRES * NRES;

    bf16x8 aq[4];
    #pragma unroll
    for (int qt = 0; qt < 4; ++qt)
        aq[qt] = *(const bf16x8*)(QOg + (size_t)(q0 + qt * 16 + mrow) * CIN + h * DH + koff);
    __syncthreads();   // msk visible

    const f32x4 zf = {0.f, 0.f, 0.f, 0.f};
    f32x4 oa[4][2];
    float ls[4];
    #pragma unroll
    for (int qt = 0; qt < 4; ++qt) { oa[qt][0] = zf; oa[qt][1] = zf; ls[qt] = 0.f; }

    u16* __restrict__ pw = &Pt[w * 64 * PST];

    for (int kt = 0; kt < 8; ++kt) {
        const int kb = kt * 32;
        bf16x8 bk0 = *(const bf16x8*)(Kb + (size_t)(kb + mrow) * CIN + h * DH + koff);
        bf16x8 bk1 = *(const bf16x8*)(Kb + (size_t)(kb + 16 + mrow) * CIN + h * DH + koff);
        bf16x8 bv0 = *(const bf16x8*)(Vt + (size_t)(h * DH + mrow) * NRES + kb + koff);
        bf16x8 bv1 = *(const bf16x8*)(Vt + (size_t)(h * DH + 16 + mrow) * NRES + kb + koff);
        const f32x4 m0 = *(const f32x4*)&msk[kb + rbase];
        const f32x4 m1 = *(const f32x4*)&msk[kb + 16 + rbase];

        #pragma unroll
        for (int qt = 0; qt < 4; ++qt) {
            const int q = q0 + qt * 16 + mrow;
            const f32x4 t0 = *(const f32x4*)(trih + (size_t)q * NRES + kb + rbase);
            const f32x4 t1 = *(const f32x4*)(trih + (size_t)q * NRES + kb + 16 + rbase);
            f32x4 s0 = MFMA(bk0, aq[qt], zf);   // r <-> k=kb+rbase+r, mrow <-> q
            f32x4 s1 = MFMA(bk1, aq[qt], zf);   // r <-> k=kb+16+rbase+r
            float part = 0.f;
            #pragma unroll
            for (int r = 0; r < 4; ++r) {
                s0[r] = __expf(s0[r] + t0[r] + m0[r] - 8.f);
                s1[r] = __expf(s1[r] + t1[r] + m1[r] - 8.f);
                part += s0[r] + s1[r];
            }
            ls[qt] += part;
            uint2 v0, v1;
            v0.x = pkbf(s0[0], s0[1]); v0.y = pkbf(s0[2], s0[3]);
            v1.x = pkbf(s1[0], s1[1]); v1.y = pkbf(s1[2], s1[3]);
            *(uint2*)&pw[(qt * 16 + mrow) * PST + rbase]      = v0;
            *(uint2*)&pw[(qt * 16 + mrow) * PST + 16 + rbase] = v1;
        }
        asm volatile("s_waitcnt lgkmcnt(0)" ::: "memory");   // P writes landed
        __builtin_amdgcn_sched_barrier(0);                   // don't hoist MFMAs above
        #pragma unroll
        for (int qt = 0; qt < 4; ++qt) {
            bf16x8 pa = *(const bf16x8*)&pw[(qt * 16 + mrow) * PST + koff];
            oa[qt][0] = MFMA(bv0, pa, oa[qt][0]);   // r <-> d=rbase+r, mrow <-> q
            oa[qt][1] = MFMA(bv1, pa, oa[qt][1]);   // r <-> d=16+rbase+r
        }
    }

    #pragma unroll
    for (int qt = 0; qt < 4; ++qt) {
        float lv = ls[qt];
        lv += __shfl_xor(lv, 16, 64);
        lv += __shfl_xor(lv, 32, 64);
        const float inv = 1.f / lv;
        const int q = q0 + qt * 16 + mrow;
        #pragma unroll
        for (int half = 0; half < 2; ++half) {
            const size_t off = (size_t)q * CIN + h * DH + half * 16 + rbase;
            const uint2 gv = *(const uint2*)&Gb[off];
            const float g0 = bf2f((u16)(gv.x)),        g1 = bf2f((u16)(gv.x >> 16));
            const float g2 = bf2f((u16)(gv.y)),        g3 = bf2f((u16)(gv.y >> 16));
            uint2 ov;
            ov.x = pkbf(oa[qt][half][0] * inv * g0, oa[qt][half][1] * inv * g1);
            ov.y = pkbf(oa[qt][half][2] * inv * g2, oa[qt][half][3] * inv * g3);
            *(uint2*)&QOg[off] = ov;
        }
    }
}

// ===========================================================================
// Kernel 4: output projection (R5, kept). out = gatedO(bf16) * Wo^T + bo.
// ===========================================================================
__global__ __launch_bounds__(256, 4) void gout(
    const u16* __restrict__ ws, const float* __restrict__ bo,
    float* __restrict__ out)
{
    const int t = threadIdx.x, lane = t & 63, w = t >> 6;
    const int mrow = lane & 15, grp = lane >> 4;
    const int koff = grp * 8, rbase = grp * 4;
    const int r0 = blockIdx.x * 128 + w * 32;
    const u16* __restrict__ Wo = ws + U_WWO;
    const u16* __restrict__ QOg = ws + U_QB;

    const f32x4 zf = {0.f, 0.f, 0.f, 0.f};
    f32x4 acc[2][8];
    #pragma unroll
    for (int at = 0; at < 2; ++at)
        #pragma unroll
        for (int nt = 0; nt < 8; ++nt) acc[at][nt] = zf;

    #pragma unroll
    for (int ks = 0; ks < 4; ++ks) {
        const int e0 = ks * 32 + koff;
        const bf16x8 a0 = *(const bf16x8*)(QOg + (size_t)(r0 + mrow) * CIN + e0);
        const bf16x8 a1 = *(const bf16x8*)(QOg + (size_t)(r0 + 16 + mrow) * CIN + e0);
        #pragma unroll
        for (int nt = 0; nt < 8; ++nt) {
            const bf16x8 bw = *(const bf16x8*)(Wo + (nt * 16 + mrow) * CIN + e0);
            acc[0][nt] = MFMA(bw, a0, acc[0][nt]);   // r <-> c=nt*16+rbase+r, mrow <-> row
            acc[1][nt] = MFMA(bw, a1, acc[1][nt]);
        }
    }

    #pragma unroll
    for (int nt = 0; nt < 8; ++nt) {
        const f32x4 bov = *(const f32x4*)&bo[nt * 16 + rbase];
        #pragma unroll
        for (int at = 0; at < 2; ++at) {
            const f32x4 v = acc[at][nt] + bov;
            *(f32x4*)&out[(size_t)(r0 + at * 16 + mrow) * CIN + nt * 16 + rbase] = v;
        }
    }
}

// ===========================================================================
// Fallback path (proven correct) for small ws_size.
// ===========================================================================
#define KST 32
#define VST 264
#define GST 136

__global__ __launch_bounds__(256, 3) void attn_fb(
    const float* __restrict__ q_x, const float* __restrict__ kv_x,
    const float* __restrict__ mask_bias, const float* __restrict__ tri_bias,
    const float* __restrict__ wq, const float* __restrict__ wk,
    const float* __restrict__ wv, float* __restrict__ o_out)
{
    const int h = blockIdx.x, n = blockIdx.y;
    const int t = threadIdx.x;
    const int lane = t & 63, w = t >> 6;
    const int mrow = lane & 15;
    const int grp  = lane >> 4;
    const int koff = grp * 8;
    const int rbase = grp * 4;
    const int q0 = w * 64;

    __shared__ u16 Ks[NRES * KST];
    __shared__ u16 Vt[DH * VST];
    __shared__ u16 Ptb[4 * 32 * PST];
    __shared__ float msk[NRES];

    if (t < 64) *(float4*)&msk[t * 4] = *(const float4*)(mask_bias + n * NRES + t * 4);

    const float* __restrict__ qxn = q_x  + (size_t)n * NRES * CIN;
    const float* __restrict__ kxn = kv_x + (size_t)n * NRES * CIN;
    const float* __restrict__ wqh = wq + h * DH * CIN;
    const float* __restrict__ wkh = wk + h * DH * CIN;
    const float* __restrict__ wvh = wv + h * DH * CIN;

    f32x4 aq_[4][2], ak_[4][2], av_[4][2];
    const f32x4 zf = {0.f, 0.f, 0.f, 0.f};
    #pragma unroll
    for (int qt = 0; qt < 4; ++qt)
        #pragma unroll
        for (int dt = 0; dt < 2; ++dt) { aq_[qt][dt] = zf; ak_[qt][dt] = zf; av_[qt][dt] = zf; }

    const float qsc = 0.17677669529663687f;
    #pragma unroll
    for (int ct = 0; ct < 4; ++ct) {
        const int c0 = ct * 32 + koff;
        bf16x8 bq0 = ldcvt8s(wqh + mrow * CIN + c0, qsc);
        bf16x8 bq1 = ldcvt8s(wqh + (16 + mrow) * CIN + c0, qsc);
        bf16x8 bk0 = ldcvt8(wkh + mrow * CIN + c0);
        bf16x8 bk1 = ldcvt8(wkh + (16 + mrow) * CIN + c0);
        bf16x8 bv0 = ldcvt8(wvh + mrow * CIN + c0);
        bf16x8 bv1 = ldcvt8(wvh + (16 + mrow) * CIN + c0);
        #pragma unroll
        for (int qt = 0; qt < 4; ++qt) {
            bf16x8 aX = ldcvt8(qxn + (q0 + qt * 16 + mrow) * CIN + c0);
            aq_[qt][0] = MFMA(aX, bq0, aq_[qt][0]);
            aq_[qt][1] = MFMA(aX, bq1, aq_[qt][1]);
            bf16x8 aK = ldcvt8(kxn + (q0 + qt * 16 + mrow) * CIN + c0);
            ak_[qt][0] = MFMA(aK, bk0, ak_[qt][0]);
            ak_[qt][1] = MFMA(aK, bk1, ak_[qt][1]);
            av_[qt][0] = MFMA(aK, bv0, av_[qt][0]);
            av_[qt][1] = MFMA(aK, bv1, av_[qt][1]);
        }
    }

    #pragma unroll
    for (int qt = 0; qt < 4; ++qt)
        #pragma unroll
        for (int dt = 0; dt < 2; ++dt)
            #pragma unroll
            for (int r = 0; r < 4; ++r) {
                const int row = q0 + qt * 16 + rbase + r;
                const int d = dt * 16 + mrow;
                Ks[row * KST + d] = f2bfu(ak_[qt][dt][r]);
                Vt[d * VST + row] = f2bfu(av_[qt][dt][r]);
            }

    u16* __restrict__ pw = &Ptb[w * 32 * PST];
    bf16x8 aq[4];
    #pragma unroll
    for (int h2 = 0; h2 < 2; ++h2) {
        #pragma unroll
        for (int j = 0; j < 2; ++j) {
            const int qt = h2 * 2 + j;
            #pragma unroll
            for (int dt = 0; dt < 2; ++dt)
                #pragma unroll
                for (int r = 0; r < 4; ++r)
                    pw[(j * 16 + rbase + r) * PST + dt * 16 + mrow] = f2bfu(aq_[qt][dt][r]);
        }
        asm volatile("s_waitcnt lgkmcnt(0)" ::: "memory");
        #pragma unroll
        for (int j = 0; j < 2; ++j)
            aq[h2 * 2 + j] = *(const bf16x8*)&pw[(j * 16 + mrow) * PST + koff];
        asm volatile("s_waitcnt lgkmcnt(0)" ::: "memory");
    }
    __syncthreads();

    f32x4 oa[4][2], ls4[4];
    #pragma unroll
    for (int qt = 0; qt < 4; ++qt) { oa[qt][0] = zf; oa[qt][1] = zf; ls4[qt] = zf; }

    const float* __restrict__ trih = tri_bias + (size_t)h * NRES * NRES;

    for (int kt = 0; kt < 8; ++kt) {
        const int kb = kt * 32;
        bf16x8 bk0 = *(const bf16x8*)&Ks[(kb + mrow) * KST + koff];
        bf16x8 bk1 = *(const bf16x8*)&Ks[(kb + 16 + mrow) * KST + koff];
        bf16x8 bv0 = *(const bf16x8*)&Vt[mrow * VST + kb + koff];
        bf16x8 bv1 = *(const bf16x8*)&Vt[(16 + mrow) * VST + kb + koff];
        const float mb0 = msk[kb + mrow] - 8.f;
        const float mb1 = msk[kb + 16 + mrow] - 8.f;

        #pragma unroll
        for (int h2 = 0; h2 < 2; ++h2) {
            float tr0[2][4], tr1[2][4];
            #pragma unroll
            for (int j = 0; j < 2; ++j) {
                const int qt = h2 * 2 + j;
                const float* __restrict__ trow =
                    trih + (q0 + qt * 16 + rbase) * NRES + kb + mrow;
                #pragma unroll
                for (int r = 0; r < 4; ++r) {
                    tr0[j][r] = trow[r * NRES];
                    tr1[j][r] = trow[r * NRES + 16];
                }
            }
            #pragma unroll
            for (int j = 0; j < 2; ++j) {
                const int qt = h2 * 2 + j;
                f32x4 s0 = MFMA(aq[qt], bk0, zf);
                f32x4 s1 = MFMA(aq[qt], bk1, zf);
                #pragma unroll
                for (int r = 0; r < 4; ++r) {
                    s0[r] = __expf(s0[r] + tr0[j][r] + mb0);
                    s1[r] = __expf(s1[r] + tr1[j][r] + mb1);
                }
                ls4[qt] += s0 + s1;
                #pragma unroll
                for (int r = 0; r < 4; ++r) {
                    pw[(j * 16 + rbase + r) * PST + mrow]      = f2bfu(s0[r]);
                    pw[(j * 16 + rbase + r) * PST + 16 + mrow] = f2bfu(s1[r]);
                }
            }
            asm volatile("s_waitcnt lgkmcnt(0)" ::: "memory");
            #pragma unroll
            for (int j = 0; j < 2; ++j) {
                const int qt = h2 * 2 + j;
                bf16x8 pa = *(const bf16x8*)&pw[(j * 16 + mrow) * PST + koff];
                oa[qt][0] = MFMA(pa, bv0, oa[qt][0]);
                oa[qt][1] = MFMA(pa, bv1, oa[qt][1]);
            }
        }
    }

    float* __restrict__ orow = o_out + (size_t)n * NRES * CIN + h * DH;
    #pragma unroll
    for (int qt = 0; qt < 4; ++qt) {
        f32x4 lv = ls4[qt];
        #pragma unroll
        for (int xm = 1; xm < 16; xm <<= 1) {
            lv[0] += __shfl_xor(lv[0], xm, 64);
            lv[1] += __shfl_xor(lv[1], xm, 64);
            lv[2] += __shfl_xor(lv[2], xm, 64);
            lv[3] += __shfl_xor(lv[3], xm, 64);
        }
        #pragma unroll
        for (int r = 0; r < 4; ++r) {
            const float inv = 1.f / lv[r];
            const int q = q0 + qt * 16 + rbase + r;
            orow[q * CIN + mrow]      = oa[qt][0][r] * inv;
            orow[q * CIN + 16 + mrow] = oa[qt][1][r] * inv;
        }
    }
}

__global__ __launch_bounds__(256, 4) void gate_fb(
    const float* __restrict__ q_x, const float* __restrict__ wg,
    const float* __restrict__ bg, const float* __restrict__ wo,
    const float* __restrict__ bo, float* io)
{
    const int t = threadIdx.x;
    const int lane = t & 63, w = t >> 6;
    const int mrow = lane & 15, grp = lane >> 4;
    const int koff = grp * 8, rbase = grp * 4;
    const int r0 = blockIdx.x * 128 + w * 32;

    __shared__ u16 Gt[4 * 32 * GST];
    u16* __restrict__ gw = &Gt[w * 32 * GST];

    const f32x4 zf = {0.f, 0.f, 0.f, 0.f};
    f32x4 acc[2][8];
    #pragma unroll
    for (int at = 0; at < 2; ++at)
        #pragma unroll
        for (int nt = 0; nt < 8; ++nt) acc[at][nt] = zf;

    #pragma unroll
    for (int ks = 0; ks < 4; ++ks) {
        const int c0 = ks * 32 + koff;
        bf16x8 ax0 = ldcvt8(q_x + (size_t)(r0 + mrow) * CIN + c0);
        bf16x8 ax1 = ldcvt8(q_x + (size_t)(r0 + 16 + mrow) * CIN + c0);
        #pragma unroll
        for (int nt = 0; nt < 8; ++nt) {
            bf16x8 bw = ldcvt8(wg + (nt * 16 + mrow) * CIN + c0);
            acc[0][nt] = MFMA(ax0, bw, acc[0][nt]);
            acc[1][nt] = MFMA(ax1, bw, acc[1][nt]);
        }
    }

    #pragma unroll
    for (int nt = 0; nt < 8; ++nt) {
        const float bge = bg[nt * 16 + mrow];
        #pragma unroll
        for (int at = 0; at < 2; ++at)
            #pragma unroll
            for (int r = 0; r < 4; ++r) {
                const int qg = r0 + at * 16 + rbase + r;
                const float ov = io[(size_t)qg * CIN + nt * 16 + mrow];
                const float g = 1.f / (1.f + __expf(-(acc[at][nt][r] + bge)));
                gw[(at * 16 + rbase + r) * GST + nt * 16 + mrow] = f2bfu(ov * g);
            }
    }
    asm volatile("s_waitcnt lgkmcnt(0)" ::: "memory");

    f32x4 acc2[2][8];
    #pragma unroll
    for (int at = 0; at < 2; ++at)
        #pragma unroll
        for (int nt = 0; nt < 8; ++nt) acc2[at][nt] = zf;

    #pragma unroll
    for (int ks = 0; ks < 4; ++ks) {
        const int e0 = ks * 32 + koff;
        bf16x8 ag0 = *(const bf16x8*)&gw[mrow * GST + e0];
        bf16x8 ag1 = *(const bf16x8*)&gw[(16 + mrow) * GST + e0];
        #pragma unroll
        for (int nt = 0; nt < 8; ++nt) {
            bf16x8 bw = ldcvt8(wo + (nt * 16 + mrow) * CIN + e0);
            acc2[0][nt] = MFMA(ag0, bw, acc2[0][nt]);
            acc2[1][nt] = MFMA(ag1, bw, acc2[1][nt]);
        }
    }

    #pragma unroll
    for (int nt = 0; nt < 8; ++nt) {
        const float boc = bo[nt * 16 + mrow];
        #pragma unroll
        for (int at = 0; at < 2; ++at)
            #pragma unroll
            for (int r = 0; r < 4; ++r)
                io[(size_t)(r0 + at * 16 + rbase + r) * CIN + nt * 16 + mrow] =
                    acc2[at][nt][r] + boc;
    }
}

extern "C" void kernel_launch(void* const* d_in, const int* in_sizes, int n_in,
                              void* d_out, int out_size, void* d_ws, size_t ws_size,
                              hipStream_t stream) {
    const float* q_x  = (const float*)d_in[0];
    const float* kv_x = (const float*)d_in[1];
    const float* mask = (const float*)d_in[2];
    const float* tri  = (const float*)d_in[3];
    const float* wq   = (const float*)d_in[4];
    const float* wk   = (const float*)d_in[5];
    const float* wv   = (const float*)d_in[6];
    const float* wg   = (const float*)d_in[7];
    const float* bg   = (const float*)d_in[8];
    const float* wo   = (const float*)d_in[9];
    const float* bo   = (const float*)d_in[10];
    float* out = (float*)d_out;

    if (ws_size >= WS_NEED) {
        u16* ws16 = (u16*)d_ws;
        wconv<<<40, 256, 0, stream>>>(wq, wk, wv, wg, wo, ws16);
        proj<<<dim3(1024, 2), 256, 0, stream>>>(q_x, kv_x, bg, ws16);
        flash<<<dim3(NH, NRES), 256, 0, stream>>>(ws16, mask, tri);
        gout<<<512, 256, 0, stream>>>(ws16, bo, out);
    } else {
        attn_fb<<<dim3(NH, NRES), 256, 0, stream>>>(q_x, kv_x, mask, tri, wq, wk, wv, out);
        gate_fb<<<(NRES * NRES) / 128, 256, 0, stream>>>(q_x, wg, bg, wo, bo, out);
    }
}